// Round 13
// baseline (442.479 us; speedup 1.0000x reference)
//
#include <hip/hip_runtime.h>

// DGMC: B=4, NS=NT=512, D_IN=128, C1=64, R=C2=32, E=32768, STEPS=10
// Pairwise MLP decomposition: upd[s,t] = mb2 + sum_j relu(Ps[s,j]-Pt[t,j])*mw2[j]
//   with Ps = (o_s@mw1)+mb1, Pt = o_t@mw1.
// Round 13: psi2s restructured per-node-all-steps -- one wave carries 10
// step-accumulators through ONE pass over the node's edge list (edge
// metadata read once, 40 independent r-row loads in flight per unroll).
// Rest identical to r12 (best measured, 425us). Lessons held: no hot-path
// device atomics (r3), full-grid occupancy (r4/r8), parallel CSR (r9),
// separate k_red -- never widen the critical gather (r6/r10), 8-deep
// gather ILP (r12).

constexpr int kB = 4;
constexpr int kNS = 512;
constexpr int kNT = 512;
constexpr int kDin = 128;
constexpr int kC1 = 64;
constexpr int kR = 32;
constexpr int kC2 = 32;
constexpr int kE = 32768;
constexpr int kSteps = 10;
constexpr int kN = kB * kNS;              // 2048 nodes per side
constexpr int kEP = kE + 16 * kN;         // padded CSR capacity per graph
constexpr int kChunkStride = kR * kN;     // floats per rt partial chunk (65536)

// ---------------- CSR build (parallel, 3 kernels + memset) ----------------
__global__ void k_hist(const int* __restrict__ ei_s, const int* __restrict__ ei_t,
                       int* __restrict__ deg) {
  int g = blockIdx.y;
  const int* dst = (g ? ei_t : ei_s) + kE;
  int e = blockIdx.x * 256 + threadIdx.x;
  atomicAdd(&deg[g * kN + dst[e]], 1);
}

// prefix sum with degree padded to multiple of 16
__global__ void k_scan(const int* __restrict__ deg, int* __restrict__ off,
                       int* __restrict__ cur) {
  int g = blockIdx.x;
  const int* d = deg + g * kN;
  int* o = off + g * (kN + 1);
  int* c = cur + g * kN;
  __shared__ int sums[256];
  int tid = threadIdx.x;
  int loc[8];
  int s = 0;
#pragma unroll
  for (int i = 0; i < 8; ++i) {
    loc[i] = (d[tid * 8 + i] + 15) & ~15;  // pad to x16
    s += loc[i];
  }
  sums[tid] = s;
  __syncthreads();
  for (int st = 1; st < 256; st <<= 1) {
    int v = (tid >= st) ? sums[tid - st] : 0;
    __syncthreads();
    sums[tid] += v;
    __syncthreads();
  }
  int base = (tid > 0) ? sums[tid - 1] : 0;
#pragma unroll
  for (int i = 0; i < 8; ++i) {
    int idx = tid * 8 + i;
    o[idx] = base;
    c[idx] = base;
    base += loc[i];
  }
  if (tid == 255) o[kN] = base;
}

__global__ void k_scatter(const int* __restrict__ ei_s, const int* __restrict__ ei_t,
                          const float* __restrict__ ea_s, const float* __restrict__ ea_t,
                          int* __restrict__ cur, int* __restrict__ srcs,
                          float* __restrict__ eaw) {
  int g = blockIdx.y;
  const int* ei = g ? ei_t : ei_s;
  const float* ea = g ? ea_t : ea_s;
  int e = blockIdx.x * 256 + threadIdx.x;
  int d = ei[kE + e];
  int srcv = ei[e];
  int pos = atomicAdd(&cur[g * kN + d], 1);
  srcs[g * kEP + pos] = srcv;
  eaw[g * kEP + pos] = ea[e];
}

// ---------------- psi2 core: P[n] = relu((vin[n]+agg) @ W2) @ mw1 (+mb1) ----
// degree padded to x16: each 32-lane half does an 8-unrolled gather.
__device__ __forceinline__ void psi2_node(
    int n, const float* __restrict__ vin, const int* __restrict__ sr,
    const float* __restrict__ ew, const int* __restrict__ o,
    const float* __restrict__ W2, const float* __restrict__ mw1,
    const float* __restrict__ mb1, float* __restrict__ Pout) {
  int lane = threadIdx.x & 63;
  int f = lane & 31, hh = lane >> 5;
  int beg = o[n], end = o[n + 1];
  float m = 0.f;
  for (int b0 = beg + hh * 8; b0 < end; b0 += 16) {
#pragma unroll
    for (int q = 0; q < 8; ++q)
      m += vin[(size_t)sr[b0 + q] * kR + f] * ew[b0 + q];
  }
  m += __shfl_down(m, 32, 64);
  float v = vin[(size_t)n * kR + f] + m;  // valid on lanes 0..31
  float acc = 0.f;
#pragma unroll
  for (int k = 0; k < kC2; ++k) acc += __shfl(v, k, 64) * W2[k * kC2 + f];
  float ov = fmaxf(acc, 0.f);
  float p = mb1 ? mb1[f] : 0.f;
#pragma unroll
  for (int k = 0; k < kC2; ++k) p += __shfl(ov, k, 64) * mw1[k * kC2 + f];
  if (lane < 32) Pout[(size_t)n * kC2 + f] = p;
}

// ---- fused pre-kernel: blocks [0,2048) = psi1 (2 nodes/block);
//      blocks [2048, 2560) = psi2s all-steps (1 node/wave, 10 accumulators) --
__global__ __launch_bounds__(256) void k_pre(
    const float* __restrict__ x_s, const float* __restrict__ x_t,
    const float* __restrict__ r, const int* __restrict__ srcs,
    const float* __restrict__ eaw, const int* __restrict__ off,
    const float* __restrict__ W1, const float* __restrict__ W2,
    const float* __restrict__ mw1, const float* __restrict__ mb1,
    float* __restrict__ h, float* __restrict__ PsAll) {
  int bid = blockIdx.x, tid = threadIdx.x;
  if (bid < 2048) {
    // psi1: h = relu((x + agg) @ W1); 2 nodes per block (128 threads each)
    int g = bid >> 10;                 // side
    int n = (bid & 1023) * 2 + (tid >> 7);
    int f = tid & 127;
    const float* x = g ? x_t : x_s;
    const int* sr = srcs + g * kEP;
    const float* ew = eaw + g * kEP;
    const int* o = off + g * (kN + 1);
    float* ho = h + (size_t)g * kN * kC1;
    __shared__ float y[2][kDin];
    int beg = o[n], end = o[n + 1];
    float xself = x[(size_t)n * kDin + f];
    float m = 0.f;
    for (int idx = beg; idx < end; idx += 8) {  // padded x16 -> safe 8-unroll
      float a0 = x[(size_t)sr[idx + 0] * kDin + f] * ew[idx + 0];
      float a1 = x[(size_t)sr[idx + 1] * kDin + f] * ew[idx + 1];
      float a2 = x[(size_t)sr[idx + 2] * kDin + f] * ew[idx + 2];
      float a3 = x[(size_t)sr[idx + 3] * kDin + f] * ew[idx + 3];
      float a4 = x[(size_t)sr[idx + 4] * kDin + f] * ew[idx + 4];
      float a5 = x[(size_t)sr[idx + 5] * kDin + f] * ew[idx + 5];
      float a6 = x[(size_t)sr[idx + 6] * kDin + f] * ew[idx + 6];
      float a7 = x[(size_t)sr[idx + 7] * kDin + f] * ew[idx + 7];
      m += ((a0 + a1) + (a2 + a3)) + ((a4 + a5) + (a6 + a7));
    }
    y[tid >> 7][f] = xself + m;
    __syncthreads();
    if (f < kC1) {
      const float* yy = y[tid >> 7];
      float acc = 0.f;
#pragma unroll 16
      for (int k = 0; k < kDin; ++k) acc += yy[k] * W1[k * kC1 + f];
      ho[(size_t)n * kC1 + f] = fmaxf(acc, 0.f);
    }
  } else {
    // psi2s all-steps: node n = (bid-2048)*4 + wave; 10 step-accumulators
    // carried through ONE pass over the edge list (metadata read once,
    // 4 edges x 10 steps = 40 independent loads in flight per unroll).
    int n = (bid - 2048) * 4 + (tid >> 6);
    int lane = tid & 63;
    int f = lane & 31, hh = lane >> 5;
    const int* o = off;
    int beg = o[n], end = o[n + 1];
    float m[kSteps];
#pragma unroll
    for (int st = 0; st < kSteps; ++st) m[st] = 0.f;
    for (int b0 = beg + hh * 4; b0 < end; b0 += 8) {  // padded x16 -> x8 ok
      int s0 = srcs[b0 + 0], s1 = srcs[b0 + 1], s2 = srcs[b0 + 2], s3 = srcs[b0 + 3];
      float w0 = eaw[b0 + 0], w1 = eaw[b0 + 1], w2 = eaw[b0 + 2], w3 = eaw[b0 + 3];
      const float* r0 = r + (size_t)s0 * kR + f;
      const float* r1 = r + (size_t)s1 * kR + f;
      const float* r2 = r + (size_t)s2 * kR + f;
      const float* r3 = r + (size_t)s3 * kR + f;
#pragma unroll
      for (int st = 0; st < kSteps; ++st) {
        size_t so = (size_t)st * kN * kR;
        m[st] += r0[so] * w0 + r1[so] * w1 + r2[so] * w2 + r3[so] * w3;
      }
    }
#pragma unroll
    for (int st = 0; st < kSteps; ++st) m[st] += __shfl_down(m[st], 32, 64);
    float bias = mb1[f];
#pragma unroll
    for (int st = 0; st < kSteps; ++st) {
      float v = r[(size_t)st * kN * kR + (size_t)n * kR + f] + m[st];
      float acc = 0.f;
#pragma unroll
      for (int k = 0; k < kC2; ++k) acc += __shfl(v, k, 64) * W2[k * kC2 + f];
      float ov = fmaxf(acc, 0.f);
      float p = bias;
#pragma unroll
      for (int k = 0; k < kC2; ++k) p += __shfl(ov, k, 64) * mw1[k * kC2 + f];
      if (lane < 32) PsAll[(size_t)st * kN * kR + (size_t)n * kC2 + f] = p;
    }
  }
}

// ------- S_hat0 = h_s @ h_t^T; also emits 8-chunk row stats (64-col chunks) --
__global__ __launch_bounds__(256) void k_shat0(const float* __restrict__ h,
                                               float* __restrict__ Shat,
                                               float* __restrict__ pstatm,
                                               float* __restrict__ pstatl) {
  int b = blockIdx.z, s0 = blockIdx.y * 64, t0 = blockIdx.x * 64;
  const float* hs = h + (size_t)(b * kNS + s0) * kC1;
  const float* ht = h + (size_t)kN * kC1 + (size_t)(b * kNT + t0) * kC1;
  __shared__ float As[64 * 68];
  __shared__ float Bs[64 * 68];
  int tid = threadIdx.x;
#pragma unroll
  for (int k2 = 0; k2 < 4; ++k2) {
    int idx = tid + k2 * 256;
    int row = idx >> 4, c4 = idx & 15;
    float4 va = *(const float4*)(hs + (size_t)row * kC1 + c4 * 4);
    *(float4*)&As[row * 68 + c4 * 4] = va;
    float4 vb = *(const float4*)(ht + (size_t)row * kC1 + c4 * 4);
    *(float4*)&Bs[row * 68 + c4 * 4] = vb;
  }
  __syncthreads();
  int ts = tid >> 4, tt = tid & 15;
  float acc[4][4] = {};
#pragma unroll
  for (int cc = 0; cc < 16; ++cc) {
    float4 a[4], bt[4];
#pragma unroll
    for (int i = 0; i < 4; ++i) a[i] = *(const float4*)&As[(ts * 4 + i) * 68 + cc * 4];
#pragma unroll
    for (int k = 0; k < 4; ++k) bt[k] = *(const float4*)&Bs[(tt + 16 * k) * 68 + cc * 4];
#pragma unroll
    for (int i = 0; i < 4; ++i)
#pragma unroll
      for (int k = 0; k < 4; ++k)
        acc[i][k] += a[i].x * bt[k].x + a[i].y * bt[k].y + a[i].z * bt[k].z + a[i].w * bt[k].w;
  }
#pragma unroll
  for (int i = 0; i < 4; ++i) {
    int s = s0 + ts * 4 + i;
    float* row = Shat + (size_t)(b * kNS + s) * kNT;
#pragma unroll
    for (int k = 0; k < 4; ++k) row[t0 + tt + 16 * k] = acc[i][k];
  }
#pragma unroll
  for (int i = 0; i < 4; ++i) {
    float mm = fmaxf(fmaxf(acc[i][0], acc[i][1]), fmaxf(acc[i][2], acc[i][3]));
#pragma unroll
    for (int o2 = 8; o2; o2 >>= 1) mm = fmaxf(mm, __shfl_xor(mm, o2, 64));
    float se = 0.f;
#pragma unroll
    for (int k = 0; k < 4; ++k) se += __expf(acc[i][k] - mm);
#pragma unroll
    for (int o2 = 8; o2; o2 >>= 1) se += __shfl_xor(se, o2, 64);
    if (tt == 0) {
      int grow = b * kNS + s0 + ts * 4 + i;
      pstatm[blockIdx.x * kN + grow] = mm;
      pstatl[blockIdx.x * kN + grow] = se;
    }
  }
}

// ---- rt partials: part[cs][j][gcol] = (64-s-chunk of softmax(S))^T r ----
// 32-col tiles -> 512 blocks (2/CU).
__global__ __launch_bounds__(256) void k_rt(const float* __restrict__ Shat,
                                            const float* __restrict__ pstatm,
                                            const float* __restrict__ pstatl,
                                            const float* __restrict__ ri,
                                            float* __restrict__ part, int nc,
                                            float* __restrict__ Sout) {
  int b = blockIdx.z, cs = blockIdx.y, s0 = cs * 64, t0 = blockIdx.x * 32;
  __shared__ float Wt[64 * 32];
  __shared__ float rch[64 * 32];
  __shared__ float lm[64], ll[64];
  int tid = threadIdx.x;
  if (tid < 64) {
    int row = b * kNS + s0 + tid;
    float m = -3.4e38f;
    for (int c = 0; c < nc; ++c) m = fmaxf(m, pstatm[c * kN + row]);
    float l = 0.f;
    for (int c = 0; c < nc; ++c) l += __expf(pstatm[c * kN + row] - m) * pstatl[c * kN + row];
    lm[tid] = m;
    ll[tid] = 1.f / l;
  }
  __syncthreads();
#pragma unroll
  for (int k2 = 0; k2 < 2; ++k2) {
    int idx = tid + k2 * 256;          // 512 f4 = 64 rows x 32 cols
    int row = idx >> 3, c4 = idx & 7;
    int grow = b * kNS + s0 + row;
    float4 v = *(const float4*)(Shat + (size_t)grow * kNT + t0 + c4 * 4);
    float m = lm[row], l = ll[row];
    float4 wv;
    wv.x = __expf(v.x - m) * l;
    wv.y = __expf(v.y - m) * l;
    wv.z = __expf(v.z - m) * l;
    wv.w = __expf(v.w - m) * l;
    *(float4*)&Wt[row * 32 + c4 * 4] = wv;
    if (Sout) *(float4*)(Sout + (size_t)grow * kNT + t0 + c4 * 4) = wv;
    float4 rv = *(const float4*)(ri + (size_t)grow * kR + c4 * 4);
    *(float4*)&rch[row * 32 + c4 * 4] = rv;
  }
  __syncthreads();
  int t_l = tid & 31, jg = tid >> 5;   // 32 cols x 8 j-groups (4 j each)
  float4 acc = make_float4(0.f, 0.f, 0.f, 0.f);
  for (int s = 0; s < 64; ++s) {
    float wv = Wt[s * 32 + t_l];
    float4 rv = *(const float4*)&rch[s * 32 + jg * 4];  // half-wave broadcast
    acc.x += wv * rv.x; acc.y += wv * rv.y; acc.z += wv * rv.z; acc.w += wv * rv.w;
  }
  // j-major: part[cs][j][gcol] -> coalesced dword stores (32 lanes = 128B)
  int gcol = b * kNT + t0 + t_l;
  float* dst = part + (size_t)cs * kChunkStride + (size_t)jg * 4 * kN + gcol;
  dst[0] = acc.x;
  dst[(size_t)kN] = acc.y;
  dst[(size_t)2 * kN] = acc.z;
  dst[(size_t)3 * kN] = acc.w;
}

// ---------------- reduce 8 partial chunks -> rt[col*32+j] ----------------
__global__ __launch_bounds__(256) void k_red(const float* __restrict__ part,
                                             float* __restrict__ rt) {
  int idx = blockIdx.x * 256 + threadIdx.x;  // 65536 = 32 j x 2048 cols
  int j = idx >> 11, col = idx & (kN - 1);
  float s = 0.f;
#pragma unroll
  for (int cs = 0; cs < 8; ++cs) s += part[(size_t)cs * kChunkStride + idx];
  rt[(size_t)col * kR + j] = s;
}

// ---- Pt for one step from the reduced rt (t-side graph) ----
__global__ __launch_bounds__(256) void k_psi2t(
    const float* __restrict__ rt, const int* __restrict__ srcs,
    const float* __restrict__ eaw, const int* __restrict__ off,
    const float* __restrict__ W2, const float* __restrict__ mw1,
    float* __restrict__ Pt) {
  int n = blockIdx.x * 4 + (threadIdx.x >> 6);
  psi2_node(n, rt, srcs + kEP, eaw + kEP, off + (kN + 1), W2, mw1, nullptr, Pt);
}

// ---- k_upd: Shat += upd over 8 s-rows x 256 t-cols; emits 2-chunk stats ----
__global__ __launch_bounds__(256) void k_upd(
    float* __restrict__ Shat, const float* __restrict__ Ps,
    const float* __restrict__ Pt, const float* __restrict__ mw2,
    const float* __restrict__ mb2, float* __restrict__ pstatm,
    float* __restrict__ pstatl) {
  __shared__ float pts[256 * 33];  // stride 33: <=2-way bank aliasing (free)
  __shared__ float red[8 * 4];
  __shared__ float lmx[8];
  int tid = threadIdx.x;
  int g0 = blockIdx.x * 8;   // global s-row base
  int cc = blockIdx.y;       // col chunk (0/1)
  int bb = g0 >> 9;          // batch
  int c0 = cc * 256;
  const float4* PtB = (const float4*)(Pt + ((size_t)bb * kNT + c0) * kC2);
#pragma unroll
  for (int k = 0; k < 8; ++k) {
    int idx = tid + k * 256;  // 2048 float4
    int col = idx >> 3, q = idx & 7;
    float4 v = PtB[idx];
    float* d = &pts[col * 33 + q * 4];
    d[0] = v.x; d[1] = v.y; d[2] = v.z; d[3] = v.w;
  }
  // prefetch the 8 Shat rows (independent loads, all in flight)
  float old[8];
#pragma unroll
  for (int s = 0; s < 8; ++s) old[s] = Shat[(size_t)(g0 + s) * kNT + c0 + tid];
  __syncthreads();
  float pt[32];
#pragma unroll
  for (int j = 0; j < 32; ++j) pt[j] = pts[tid * 33 + j];
  float bias = mb2[0];
  float nv[8];
#pragma unroll
  for (int s = 0; s < 8; ++s) {
    const float* psr = Ps + (size_t)(g0 + s) * kC2;  // uniform -> scalar loads
    float u = 0.f;
#pragma unroll
    for (int j = 0; j < 32; ++j) u += fmaxf(psr[j] - pt[j], 0.f) * mw2[j];
    float v = old[s] + u + bias;
    Shat[(size_t)(g0 + s) * kNT + c0 + tid] = v;
    nv[s] = v;
  }
  int wv = tid >> 6, ln = tid & 63;
#pragma unroll
  for (int s = 0; s < 8; ++s) {
    float m = nv[s];
#pragma unroll
    for (int o2 = 32; o2; o2 >>= 1) m = fmaxf(m, __shfl_down(m, o2, 64));
    if (ln == 0) red[s * 4 + wv] = m;
  }
  __syncthreads();
  if (tid < 8) {
    lmx[tid] = fmaxf(fmaxf(red[tid * 4], red[tid * 4 + 1]),
                     fmaxf(red[tid * 4 + 2], red[tid * 4 + 3]));
  }
  __syncthreads();
#pragma unroll
  for (int s = 0; s < 8; ++s) {
    float e = __expf(nv[s] - lmx[s]);
#pragma unroll
    for (int o2 = 32; o2; o2 >>= 1) e += __shfl_down(e, o2, 64);
    if (ln == 0) red[s * 4 + wv] = e;
  }
  __syncthreads();
  if (tid < 8) {
    float l = red[tid * 4] + red[tid * 4 + 1] + red[tid * 4 + 2] + red[tid * 4 + 3];
    pstatm[cc * kN + g0 + tid] = lmx[tid];
    pstatl[cc * kN + g0 + tid] = l;
  }
}

// ---- final: out = softmax(Shat) using the last k_upd's 2-chunk stats ----
__global__ __launch_bounds__(256) void k_out(const float* __restrict__ Shat,
                                             const float* __restrict__ pstatm,
                                             const float* __restrict__ pstatl,
                                             float* __restrict__ out) {
  int row = blockIdx.x, tid = threadIdx.x;
  float m0 = pstatm[row], m1 = pstatm[kN + row];
  float l0 = pstatl[row], l1 = pstatl[kN + row];
  float m = fmaxf(m0, m1);
  float linv = 1.f / (__expf(m0 - m) * l0 + __expf(m1 - m) * l1);
  const float* p = Shat + (size_t)row * kNT;
  float* d = out + (size_t)row * kNT;
  d[tid] = __expf(p[tid] - m) * linv;
  d[tid + 256] = __expf(p[tid + 256] - m) * linv;
}

extern "C" void kernel_launch(void* const* d_in, const int* in_sizes, int n_in,
                              void* d_out, int out_size, void* d_ws, size_t ws_size,
                              hipStream_t stream) {
  (void)in_sizes; (void)n_in; (void)out_size; (void)ws_size;
  const float* x_s = (const float*)d_in[0];
  const int* ei_s = (const int*)d_in[1];
  const float* ea_s = (const float*)d_in[2];
  const float* x_t = (const float*)d_in[4];
  const int* ei_t = (const int*)d_in[5];
  const float* ea_t = (const float*)d_in[6];
  const float* W1 = (const float*)d_in[8];
  const float* W2 = (const float*)d_in[9];
  const float* mw1 = (const float*)d_in[10];
  const float* mb1 = (const float*)d_in[11];
  const float* mw2 = (const float*)d_in[12];
  const float* mb2 = (const float*)d_in[13];
  const float* r = (const float*)d_in[14];
  float* out = (float*)d_out;

  char* w = (char*)d_ws;
  auto alloc = [&](size_t bytes) -> void* {
    void* p = (void*)w;
    w += (bytes + 255) & ~(size_t)255;
    return p;
  };
  // deg, cur, srcs, eaw contiguous -> one memset zeroes counters AND fillers
  int* deg = (int*)alloc((size_t)2 * kN * 4);
  int* cur = (int*)alloc((size_t)2 * kN * 4);
  int* srcs = (int*)alloc((size_t)2 * kEP * 4);
  float* eaw = (float*)alloc((size_t)2 * kEP * 4);
  size_t zbytes = (size_t)((char*)(eaw + 2 * kEP) - (char*)deg);
  int* off = (int*)alloc((size_t)2 * (kN + 1) * 4);
  float* h = (float*)alloc((size_t)2 * kN * kC1 * 4);
  float* Shat = (float*)alloc((size_t)kB * kNS * kNT * 4);
  float* pstatm = (float*)alloc((size_t)8 * kN * 4);
  float* pstatl = (float*)alloc((size_t)8 * kN * 4);
  float* rt = (float*)alloc((size_t)kN * kR * 4);
  float* PsAll = (float*)alloc((size_t)kSteps * kN * kR * 4);  // 2.6 MB
  float* Pt = (float*)alloc((size_t)kN * kC2 * 4);
  float* part = (float*)alloc((size_t)8 * kChunkStride * 4);   // 2 MB

  hipMemsetAsync(deg, 0, zbytes, stream);
  k_hist<<<dim3(kE / 256, 2), 256, 0, stream>>>(ei_s, ei_t, deg);
  k_scan<<<2, 256, 0, stream>>>(deg, off, cur);
  k_scatter<<<dim3(kE / 256, 2), 256, 0, stream>>>(ei_s, ei_t, ea_s, ea_t, cur, srcs, eaw);
  k_pre<<<2560, 256, 0, stream>>>(x_s, x_t, r, srcs, eaw, off, W1, W2, mw1, mb1,
                                  h, PsAll);
  k_shat0<<<dim3(8, 8, kB), 256, 0, stream>>>(h, Shat, pstatm, pstatl);
  // initial: combine 8 stat chunks, write S_0 to out, emit rt partials
  k_rt<<<dim3(16, 8, kB), 256, 0, stream>>>(Shat, pstatm, pstatl, r, part, 8, out);
  k_red<<<kChunkStride / 256, 256, 0, stream>>>(part, rt);
  for (int i = 0; i < kSteps; ++i) {
    k_psi2t<<<kN / 4, 256, 0, stream>>>(rt, srcs, eaw, off, W2, mw1, Pt);
    k_upd<<<dim3(kN / 8, 2), 256, 0, stream>>>(Shat, PsAll + (size_t)i * kN * kR, Pt,
                                               mw2, mb2, pstatm, pstatl);
    if (i + 1 < kSteps) {
      k_rt<<<dim3(16, 8, kB), 256, 0, stream>>>(Shat, pstatm, pstatl,
                                                r + (size_t)(i + 1) * kN * kR, part,
                                                2, nullptr);
      k_red<<<kChunkStride / 256, 256, 0, stream>>>(part, rt);
    }
  }
  k_out<<<kN, 256, 0, stream>>>(Shat, pstatm, pstatl, out + (size_t)kB * kNS * kNT);
}

// Round 14
// 424.032 us; speedup vs baseline: 1.0435x; 1.0435x over previous
//
#include <hip/hip_runtime.h>

// DGMC: B=4, NS=NT=512, D_IN=128, C1=64, R=C2=32, E=32768, STEPS=10
// Pairwise MLP decomposition: upd[s,t] = mb2 + sum_j relu(Ps[s,j]-Pt[t,j])*mw2[j]
//   with Ps = (o_s@mw1)+mb1, Pt = o_t@mw1.
// Round 14: pure revert to r12 (best measured, 425.6us). r13's per-node-
// all-steps psi2s traded TLP for per-wave ILP and lost (occupancy 35->18%,
// k_pre 30->48us): for latency-bound gathers, many cheap waves beat few
// wide ones. Lessons held: no hot-path device atomics (r3), full-grid
// occupancy (r4/r8/r13), parallel CSR (r9), separate k_red -- never widen
// the critical gather (r6/r10), 8-deep gather ILP + 512-block k_rt (r12).

constexpr int kB = 4;
constexpr int kNS = 512;
constexpr int kNT = 512;
constexpr int kDin = 128;
constexpr int kC1 = 64;
constexpr int kR = 32;
constexpr int kC2 = 32;
constexpr int kE = 32768;
constexpr int kSteps = 10;
constexpr int kN = kB * kNS;              // 2048 nodes per side
constexpr int kEP = kE + 16 * kN;         // padded CSR capacity per graph
constexpr int kChunkStride = kR * kN;     // floats per rt partial chunk (65536)

// ---------------- CSR build (parallel, 3 kernels + memset) ----------------
__global__ void k_hist(const int* __restrict__ ei_s, const int* __restrict__ ei_t,
                       int* __restrict__ deg) {
  int g = blockIdx.y;
  const int* dst = (g ? ei_t : ei_s) + kE;
  int e = blockIdx.x * 256 + threadIdx.x;
  atomicAdd(&deg[g * kN + dst[e]], 1);
}

// prefix sum with degree padded to multiple of 16
__global__ void k_scan(const int* __restrict__ deg, int* __restrict__ off,
                       int* __restrict__ cur) {
  int g = blockIdx.x;
  const int* d = deg + g * kN;
  int* o = off + g * (kN + 1);
  int* c = cur + g * kN;
  __shared__ int sums[256];
  int tid = threadIdx.x;
  int loc[8];
  int s = 0;
#pragma unroll
  for (int i = 0; i < 8; ++i) {
    loc[i] = (d[tid * 8 + i] + 15) & ~15;  // pad to x16
    s += loc[i];
  }
  sums[tid] = s;
  __syncthreads();
  for (int st = 1; st < 256; st <<= 1) {
    int v = (tid >= st) ? sums[tid - st] : 0;
    __syncthreads();
    sums[tid] += v;
    __syncthreads();
  }
  int base = (tid > 0) ? sums[tid - 1] : 0;
#pragma unroll
  for (int i = 0; i < 8; ++i) {
    int idx = tid * 8 + i;
    o[idx] = base;
    c[idx] = base;
    base += loc[i];
  }
  if (tid == 255) o[kN] = base;
}

__global__ void k_scatter(const int* __restrict__ ei_s, const int* __restrict__ ei_t,
                          const float* __restrict__ ea_s, const float* __restrict__ ea_t,
                          int* __restrict__ cur, int* __restrict__ srcs,
                          float* __restrict__ eaw) {
  int g = blockIdx.y;
  const int* ei = g ? ei_t : ei_s;
  const float* ea = g ? ea_t : ea_s;
  int e = blockIdx.x * 256 + threadIdx.x;
  int d = ei[kE + e];
  int srcv = ei[e];
  int pos = atomicAdd(&cur[g * kN + d], 1);
  srcs[g * kEP + pos] = srcv;
  eaw[g * kEP + pos] = ea[e];
}

// ---------------- psi2 core: P[n] = relu((vin[n]+agg) @ W2) @ mw1 (+mb1) ----
// degree padded to x16: each 32-lane half does an 8-unrolled gather
// (8 independent loads in flight).
__device__ __forceinline__ void psi2_node(
    int n, const float* __restrict__ vin, const int* __restrict__ sr,
    const float* __restrict__ ew, const int* __restrict__ o,
    const float* __restrict__ W2, const float* __restrict__ mw1,
    const float* __restrict__ mb1, float* __restrict__ Pout) {
  int lane = threadIdx.x & 63;
  int f = lane & 31, hh = lane >> 5;
  int beg = o[n], end = o[n + 1];
  float m = 0.f;
  for (int b0 = beg + hh * 8; b0 < end; b0 += 16) {
#pragma unroll
    for (int q = 0; q < 8; ++q)
      m += vin[(size_t)sr[b0 + q] * kR + f] * ew[b0 + q];
  }
  m += __shfl_down(m, 32, 64);
  float v = vin[(size_t)n * kR + f] + m;  // valid on lanes 0..31
  float acc = 0.f;
#pragma unroll
  for (int k = 0; k < kC2; ++k) acc += __shfl(v, k, 64) * W2[k * kC2 + f];
  float ov = fmaxf(acc, 0.f);
  float p = mb1 ? mb1[f] : 0.f;
#pragma unroll
  for (int k = 0; k < kC2; ++k) p += __shfl(ov, k, 64) * mw1[k * kC2 + f];
  if (lane < 32) Pout[(size_t)n * kC2 + f] = p;
}

// ---- fused pre-kernel: blocks [0,2048) = psi1 (2 nodes/block);
//      blocks [2048, 7168) = psi2s (Ps for all 10 steps, 4 nodes/block) ----
__global__ __launch_bounds__(256) void k_pre(
    const float* __restrict__ x_s, const float* __restrict__ x_t,
    const float* __restrict__ r, const int* __restrict__ srcs,
    const float* __restrict__ eaw, const int* __restrict__ off,
    const float* __restrict__ W1, const float* __restrict__ W2,
    const float* __restrict__ mw1, const float* __restrict__ mb1,
    float* __restrict__ h, float* __restrict__ PsAll) {
  int bid = blockIdx.x, tid = threadIdx.x;
  if (bid < 2048) {
    // psi1: h = relu((x + agg) @ W1); 2 nodes per block (128 threads each)
    int g = bid >> 10;                 // side
    int n = (bid & 1023) * 2 + (tid >> 7);
    int f = tid & 127;
    const float* x = g ? x_t : x_s;
    const int* sr = srcs + g * kEP;
    const float* ew = eaw + g * kEP;
    const int* o = off + g * (kN + 1);
    float* ho = h + (size_t)g * kN * kC1;
    __shared__ float y[2][kDin];
    int beg = o[n], end = o[n + 1];
    float xself = x[(size_t)n * kDin + f];
    float m = 0.f;
    for (int idx = beg; idx < end; idx += 8) {  // padded x16 -> safe 8-unroll
      float a0 = x[(size_t)sr[idx + 0] * kDin + f] * ew[idx + 0];
      float a1 = x[(size_t)sr[idx + 1] * kDin + f] * ew[idx + 1];
      float a2 = x[(size_t)sr[idx + 2] * kDin + f] * ew[idx + 2];
      float a3 = x[(size_t)sr[idx + 3] * kDin + f] * ew[idx + 3];
      float a4 = x[(size_t)sr[idx + 4] * kDin + f] * ew[idx + 4];
      float a5 = x[(size_t)sr[idx + 5] * kDin + f] * ew[idx + 5];
      float a6 = x[(size_t)sr[idx + 6] * kDin + f] * ew[idx + 6];
      float a7 = x[(size_t)sr[idx + 7] * kDin + f] * ew[idx + 7];
      m += ((a0 + a1) + (a2 + a3)) + ((a4 + a5) + (a6 + a7));
    }
    y[tid >> 7][f] = xself + m;
    __syncthreads();
    if (f < kC1) {
      const float* yy = y[tid >> 7];
      float acc = 0.f;
#pragma unroll 16
      for (int k = 0; k < kDin; ++k) acc += yy[k] * W1[k * kC1 + f];
      ho[(size_t)n * kC1 + f] = fmaxf(acc, 0.f);
    }
  } else {
    int nn = (bid - 2048) * 4 + (tid >> 6);  // 0..20479
    int step = nn >> 11, node = nn & (kN - 1);
    psi2_node(node, r + (size_t)step * kN * kR, srcs, eaw, off, W2, mw1, mb1,
              PsAll + (size_t)step * kN * kR);
  }
}

// ------- S_hat0 = h_s @ h_t^T; also emits 8-chunk row stats (64-col chunks) --
__global__ __launch_bounds__(256) void k_shat0(const float* __restrict__ h,
                                               float* __restrict__ Shat,
                                               float* __restrict__ pstatm,
                                               float* __restrict__ pstatl) {
  int b = blockIdx.z, s0 = blockIdx.y * 64, t0 = blockIdx.x * 64;
  const float* hs = h + (size_t)(b * kNS + s0) * kC1;
  const float* ht = h + (size_t)kN * kC1 + (size_t)(b * kNT + t0) * kC1;
  __shared__ float As[64 * 68];
  __shared__ float Bs[64 * 68];
  int tid = threadIdx.x;
#pragma unroll
  for (int k2 = 0; k2 < 4; ++k2) {
    int idx = tid + k2 * 256;
    int row = idx >> 4, c4 = idx & 15;
    float4 va = *(const float4*)(hs + (size_t)row * kC1 + c4 * 4);
    *(float4*)&As[row * 68 + c4 * 4] = va;
    float4 vb = *(const float4*)(ht + (size_t)row * kC1 + c4 * 4);
    *(float4*)&Bs[row * 68 + c4 * 4] = vb;
  }
  __syncthreads();
  int ts = tid >> 4, tt = tid & 15;
  float acc[4][4] = {};
#pragma unroll
  for (int cc = 0; cc < 16; ++cc) {
    float4 a[4], bt[4];
#pragma unroll
    for (int i = 0; i < 4; ++i) a[i] = *(const float4*)&As[(ts * 4 + i) * 68 + cc * 4];
#pragma unroll
    for (int k = 0; k < 4; ++k) bt[k] = *(const float4*)&Bs[(tt + 16 * k) * 68 + cc * 4];
#pragma unroll
    for (int i = 0; i < 4; ++i)
#pragma unroll
      for (int k = 0; k < 4; ++k)
        acc[i][k] += a[i].x * bt[k].x + a[i].y * bt[k].y + a[i].z * bt[k].z + a[i].w * bt[k].w;
  }
#pragma unroll
  for (int i = 0; i < 4; ++i) {
    int s = s0 + ts * 4 + i;
    float* row = Shat + (size_t)(b * kNS + s) * kNT;
#pragma unroll
    for (int k = 0; k < 4; ++k) row[t0 + tt + 16 * k] = acc[i][k];
  }
#pragma unroll
  for (int i = 0; i < 4; ++i) {
    float mm = fmaxf(fmaxf(acc[i][0], acc[i][1]), fmaxf(acc[i][2], acc[i][3]));
#pragma unroll
    for (int o2 = 8; o2; o2 >>= 1) mm = fmaxf(mm, __shfl_xor(mm, o2, 64));
    float se = 0.f;
#pragma unroll
    for (int k = 0; k < 4; ++k) se += __expf(acc[i][k] - mm);
#pragma unroll
    for (int o2 = 8; o2; o2 >>= 1) se += __shfl_xor(se, o2, 64);
    if (tt == 0) {
      int grow = b * kNS + s0 + ts * 4 + i;
      pstatm[blockIdx.x * kN + grow] = mm;
      pstatl[blockIdx.x * kN + grow] = se;
    }
  }
}

// ---- rt partials: part[cs][j][gcol] = (64-s-chunk of softmax(S))^T r ----
// 32-col tiles -> 512 blocks (2/CU).
__global__ __launch_bounds__(256) void k_rt(const float* __restrict__ Shat,
                                            const float* __restrict__ pstatm,
                                            const float* __restrict__ pstatl,
                                            const float* __restrict__ ri,
                                            float* __restrict__ part, int nc,
                                            float* __restrict__ Sout) {
  int b = blockIdx.z, cs = blockIdx.y, s0 = cs * 64, t0 = blockIdx.x * 32;
  __shared__ float Wt[64 * 32];
  __shared__ float rch[64 * 32];
  __shared__ float lm[64], ll[64];
  int tid = threadIdx.x;
  if (tid < 64) {
    int row = b * kNS + s0 + tid;
    float m = -3.4e38f;
    for (int c = 0; c < nc; ++c) m = fmaxf(m, pstatm[c * kN + row]);
    float l = 0.f;
    for (int c = 0; c < nc; ++c) l += __expf(pstatm[c * kN + row] - m) * pstatl[c * kN + row];
    lm[tid] = m;
    ll[tid] = 1.f / l;
  }
  __syncthreads();
#pragma unroll
  for (int k2 = 0; k2 < 2; ++k2) {
    int idx = tid + k2 * 256;          // 512 f4 = 64 rows x 32 cols
    int row = idx >> 3, c4 = idx & 7;
    int grow = b * kNS + s0 + row;
    float4 v = *(const float4*)(Shat + (size_t)grow * kNT + t0 + c4 * 4);
    float m = lm[row], l = ll[row];
    float4 wv;
    wv.x = __expf(v.x - m) * l;
    wv.y = __expf(v.y - m) * l;
    wv.z = __expf(v.z - m) * l;
    wv.w = __expf(v.w - m) * l;
    *(float4*)&Wt[row * 32 + c4 * 4] = wv;
    if (Sout) *(float4*)(Sout + (size_t)grow * kNT + t0 + c4 * 4) = wv;
    float4 rv = *(const float4*)(ri + (size_t)grow * kR + c4 * 4);
    *(float4*)&rch[row * 32 + c4 * 4] = rv;
  }
  __syncthreads();
  int t_l = tid & 31, jg = tid >> 5;   // 32 cols x 8 j-groups (4 j each)
  float4 acc = make_float4(0.f, 0.f, 0.f, 0.f);
  for (int s = 0; s < 64; ++s) {
    float wv = Wt[s * 32 + t_l];
    float4 rv = *(const float4*)&rch[s * 32 + jg * 4];  // half-wave broadcast
    acc.x += wv * rv.x; acc.y += wv * rv.y; acc.z += wv * rv.z; acc.w += wv * rv.w;
  }
  // j-major: part[cs][j][gcol] -> coalesced dword stores (32 lanes = 128B)
  int gcol = b * kNT + t0 + t_l;
  float* dst = part + (size_t)cs * kChunkStride + (size_t)jg * 4 * kN + gcol;
  dst[0] = acc.x;
  dst[(size_t)kN] = acc.y;
  dst[(size_t)2 * kN] = acc.z;
  dst[(size_t)3 * kN] = acc.w;
}

// ---------------- reduce 8 partial chunks -> rt[col*32+j] ----------------
__global__ __launch_bounds__(256) void k_red(const float* __restrict__ part,
                                             float* __restrict__ rt) {
  int idx = blockIdx.x * 256 + threadIdx.x;  // 65536 = 32 j x 2048 cols
  int j = idx >> 11, col = idx & (kN - 1);
  float s = 0.f;
#pragma unroll
  for (int cs = 0; cs < 8; ++cs) s += part[(size_t)cs * kChunkStride + idx];
  rt[(size_t)col * kR + j] = s;
}

// ---- Pt for one step from the reduced rt (t-side graph) ----
__global__ __launch_bounds__(256) void k_psi2t(
    const float* __restrict__ rt, const int* __restrict__ srcs,
    const float* __restrict__ eaw, const int* __restrict__ off,
    const float* __restrict__ W2, const float* __restrict__ mw1,
    float* __restrict__ Pt) {
  int n = blockIdx.x * 4 + (threadIdx.x >> 6);
  psi2_node(n, rt, srcs + kEP, eaw + kEP, off + (kN + 1), W2, mw1, nullptr, Pt);
}

// ---- k_upd: Shat += upd over 8 s-rows x 256 t-cols; emits 2-chunk stats ----
__global__ __launch_bounds__(256) void k_upd(
    float* __restrict__ Shat, const float* __restrict__ Ps,
    const float* __restrict__ Pt, const float* __restrict__ mw2,
    const float* __restrict__ mb2, float* __restrict__ pstatm,
    float* __restrict__ pstatl) {
  __shared__ float pts[256 * 33];  // stride 33: <=2-way bank aliasing (free)
  __shared__ float red[8 * 4];
  __shared__ float lmx[8];
  int tid = threadIdx.x;
  int g0 = blockIdx.x * 8;   // global s-row base
  int cc = blockIdx.y;       // col chunk (0/1)
  int bb = g0 >> 9;          // batch
  int c0 = cc * 256;
  const float4* PtB = (const float4*)(Pt + ((size_t)bb * kNT + c0) * kC2);
#pragma unroll
  for (int k = 0; k < 8; ++k) {
    int idx = tid + k * 256;  // 2048 float4
    int col = idx >> 3, q = idx & 7;
    float4 v = PtB[idx];
    float* d = &pts[col * 33 + q * 4];
    d[0] = v.x; d[1] = v.y; d[2] = v.z; d[3] = v.w;
  }
  // prefetch the 8 Shat rows (independent loads, all in flight)
  float old[8];
#pragma unroll
  for (int s = 0; s < 8; ++s) old[s] = Shat[(size_t)(g0 + s) * kNT + c0 + tid];
  __syncthreads();
  float pt[32];
#pragma unroll
  for (int j = 0; j < 32; ++j) pt[j] = pts[tid * 33 + j];
  float bias = mb2[0];
  float nv[8];
#pragma unroll
  for (int s = 0; s < 8; ++s) {
    const float* psr = Ps + (size_t)(g0 + s) * kC2;  // uniform -> scalar loads
    float u = 0.f;
#pragma unroll
    for (int j = 0; j < 32; ++j) u += fmaxf(psr[j] - pt[j], 0.f) * mw2[j];
    float v = old[s] + u + bias;
    Shat[(size_t)(g0 + s) * kNT + c0 + tid] = v;
    nv[s] = v;
  }
  int wv = tid >> 6, ln = tid & 63;
#pragma unroll
  for (int s = 0; s < 8; ++s) {
    float m = nv[s];
#pragma unroll
    for (int o2 = 32; o2; o2 >>= 1) m = fmaxf(m, __shfl_down(m, o2, 64));
    if (ln == 0) red[s * 4 + wv] = m;
  }
  __syncthreads();
  if (tid < 8) {
    lmx[tid] = fmaxf(fmaxf(red[tid * 4], red[tid * 4 + 1]),
                     fmaxf(red[tid * 4 + 2], red[tid * 4 + 3]));
  }
  __syncthreads();
#pragma unroll
  for (int s = 0; s < 8; ++s) {
    float e = __expf(nv[s] - lmx[s]);
#pragma unroll
    for (int o2 = 32; o2; o2 >>= 1) e += __shfl_down(e, o2, 64);
    if (ln == 0) red[s * 4 + wv] = e;
  }
  __syncthreads();
  if (tid < 8) {
    float l = red[tid * 4] + red[tid * 4 + 1] + red[tid * 4 + 2] + red[tid * 4 + 3];
    pstatm[cc * kN + g0 + tid] = lmx[tid];
    pstatl[cc * kN + g0 + tid] = l;
  }
}

// ---- final: out = softmax(Shat) using the last k_upd's 2-chunk stats ----
__global__ __launch_bounds__(256) void k_out(const float* __restrict__ Shat,
                                             const float* __restrict__ pstatm,
                                             const float* __restrict__ pstatl,
                                             float* __restrict__ out) {
  int row = blockIdx.x, tid = threadIdx.x;
  float m0 = pstatm[row], m1 = pstatm[kN + row];
  float l0 = pstatl[row], l1 = pstatl[kN + row];
  float m = fmaxf(m0, m1);
  float linv = 1.f / (__expf(m0 - m) * l0 + __expf(m1 - m) * l1);
  const float* p = Shat + (size_t)row * kNT;
  float* d = out + (size_t)row * kNT;
  d[tid] = __expf(p[tid] - m) * linv;
  d[tid + 256] = __expf(p[tid + 256] - m) * linv;
}

extern "C" void kernel_launch(void* const* d_in, const int* in_sizes, int n_in,
                              void* d_out, int out_size, void* d_ws, size_t ws_size,
                              hipStream_t stream) {
  (void)in_sizes; (void)n_in; (void)out_size; (void)ws_size;
  const float* x_s = (const float*)d_in[0];
  const int* ei_s = (const int*)d_in[1];
  const float* ea_s = (const float*)d_in[2];
  const float* x_t = (const float*)d_in[4];
  const int* ei_t = (const int*)d_in[5];
  const float* ea_t = (const float*)d_in[6];
  const float* W1 = (const float*)d_in[8];
  const float* W2 = (const float*)d_in[9];
  const float* mw1 = (const float*)d_in[10];
  const float* mb1 = (const float*)d_in[11];
  const float* mw2 = (const float*)d_in[12];
  const float* mb2 = (const float*)d_in[13];
  const float* r = (const float*)d_in[14];
  float* out = (float*)d_out;

  char* w = (char*)d_ws;
  auto alloc = [&](size_t bytes) -> void* {
    void* p = (void*)w;
    w += (bytes + 255) & ~(size_t)255;
    return p;
  };
  // deg, cur, srcs, eaw contiguous -> one memset zeroes counters AND fillers
  int* deg = (int*)alloc((size_t)2 * kN * 4);
  int* cur = (int*)alloc((size_t)2 * kN * 4);
  int* srcs = (int*)alloc((size_t)2 * kEP * 4);
  float* eaw = (float*)alloc((size_t)2 * kEP * 4);
  size_t zbytes = (size_t)((char*)(eaw + 2 * kEP) - (char*)deg);
  int* off = (int*)alloc((size_t)2 * (kN + 1) * 4);
  float* h = (float*)alloc((size_t)2 * kN * kC1 * 4);
  float* Shat = (float*)alloc((size_t)kB * kNS * kNT * 4);
  float* pstatm = (float*)alloc((size_t)8 * kN * 4);
  float* pstatl = (float*)alloc((size_t)8 * kN * 4);
  float* rt = (float*)alloc((size_t)kN * kR * 4);
  float* PsAll = (float*)alloc((size_t)kSteps * kN * kR * 4);  // 2.6 MB
  float* Pt = (float*)alloc((size_t)kN * kC2 * 4);
  float* part = (float*)alloc((size_t)8 * kChunkStride * 4);   // 2 MB

  hipMemsetAsync(deg, 0, zbytes, stream);
  k_hist<<<dim3(kE / 256, 2), 256, 0, stream>>>(ei_s, ei_t, deg);
  k_scan<<<2, 256, 0, stream>>>(deg, off, cur);
  k_scatter<<<dim3(kE / 256, 2), 256, 0, stream>>>(ei_s, ei_t, ea_s, ea_t, cur, srcs, eaw);
  k_pre<<<7168, 256, 0, stream>>>(x_s, x_t, r, srcs, eaw, off, W1, W2, mw1, mb1,
                                  h, PsAll);
  k_shat0<<<dim3(8, 8, kB), 256, 0, stream>>>(h, Shat, pstatm, pstatl);
  // initial: combine 8 stat chunks, write S_0 to out, emit rt partials
  k_rt<<<dim3(16, 8, kB), 256, 0, stream>>>(Shat, pstatm, pstatl, r, part, 8, out);
  k_red<<<kChunkStride / 256, 256, 0, stream>>>(part, rt);
  for (int i = 0; i < kSteps; ++i) {
    k_psi2t<<<kN / 4, 256, 0, stream>>>(rt, srcs, eaw, off, W2, mw1, Pt);
    k_upd<<<dim3(kN / 8, 2), 256, 0, stream>>>(Shat, PsAll + (size_t)i * kN * kR, Pt,
                                               mw2, mb2, pstatm, pstatl);
    if (i + 1 < kSteps) {
      k_rt<<<dim3(16, 8, kB), 256, 0, stream>>>(Shat, pstatm, pstatl,
                                                r + (size_t)(i + 1) * kN * kR, part,
                                                2, nullptr);
      k_red<<<kChunkStride / 256, 256, 0, stream>>>(part, rt);
    }
  }
  k_out<<<kN, 256, 0, stream>>>(Shat, pstatm, pstatl, out + (size_t)kB * kNS * kNT);
}